// Round 11
// baseline (205.040 us; speedup 1.0000x reference)
//
#include <hip/hip_runtime.h>
#include <hip/hip_bf16.h>
#include <math.h>

#define S_LEN  2048
#define HQ     16
#define HKV    2
#define GQ     8      // Hq / Hkv
#define DH     64
#define LCC    32     // compression block
#define CSTRIDE 16
#define SC     127    // (S - LC)/STRIDE + 1
#define LB     64     // selection block
#define KSEL   8
#define WIN    512
#define NB     32     // S / LB
#define NOUT   31     // pooled length before pad
#define QTS    8      // queries per block in selswa kernel
#define SCALE  0.125f
#define QSC    (0.125f * 1.4426950408889634f)   // SCALE * log2(e): exp2-domain scores

typedef __attribute__((ext_vector_type(8))) short bf16x8;
typedef __attribute__((ext_vector_type(4))) float f32x4;
typedef unsigned short u16;
typedef unsigned int   u32;

__device__ __forceinline__ u16 f2bf(float f) {
  u32 u = __float_as_uint(f);
  return (u16)((u + 0x7FFFu + ((u >> 16) & 1u)) >> 16);
}

__device__ __forceinline__ float fexp2(float x) {
  float r;
  asm("v_exp_f32 %0, %1" : "=v"(r) : "v"(x));
  return r;
}

__device__ __forceinline__ void gl_lds16(const void* g, void* lds) {
  __builtin_amdgcn_global_load_lds(
      (const __attribute__((address_space(1))) void*)g,
      (__attribute__((address_space(3))) void*)lds, 16, 0, 0);
}

// ---------------- Stage A: conv1d compression (split-K, 256 thr) ----------------
__global__ __launch_bounds__(256) void nsa_conv_kernel(
    const float* __restrict__ k, const float* __restrict__ v,
    const float* __restrict__ wk, const float* __restrict__ wv,
    float* __restrict__ ck, float* __restrict__ cv) {
  int c = blockIdx.x % SC;
  int h = blockIdx.x / SC;
  __shared__ float kin[LCC * DH];
  __shared__ float vin[LCC * DH];
  __shared__ float cred[128];
  int tid = threadIdx.x;
  for (int f = tid; f < LCC * DH / 4; f += 256) {
    int tt = f >> 4, i4 = f & 15;
    int row = c * CSTRIDE + tt;
    ((float4*)kin)[f] = ((const float4*)(k + ((size_t)row * HKV + h) * DH))[i4];
    ((float4*)vin)[f] = ((const float4*)(v + ((size_t)row * HKV + h) * DH))[i4];
  }
  __syncthreads();
  int o  = tid & 63;
  int kv = (tid >> 6) & 1;   // 0:k 1:v
  int uh = tid >> 7;         // u half
  const float* w  = (kv ? wv : wk) + (size_t)o * (DH * LCC) + uh * 16;
  const float* in = (kv ? vin : kin) + uh * 16 * DH;
  float acc = 0.f;
  for (int i = 0; i < DH; ++i) {
    #pragma unroll
    for (int u = 0; u < 16; ++u)
      acc = fmaf(in[u * DH + i], w[i * LCC + u], acc);
  }
  if (uh == 1) cred[tid & 127] = acc;
  __syncthreads();
  if (uh == 0) {
    acc += cred[tid & 127];
    float* dst = (kv ? cv : ck);
    dst[((size_t)h * SC + c) * DH + o] = acc;
  }
}

// ---- prep: pre-swizzled bf16 K + V^T (for global_load_lds staging) + gates ----
__global__ __launch_bounds__(256) void nsa_prep_kernel(
    const float* __restrict__ q, const float* __restrict__ k,
    const float* __restrict__ v, const float* __restrict__ wg,
    u16* __restrict__ kb, u16* __restrict__ vt, float* __restrict__ gates) {
  int id = blockIdx.x * 256 + threadIdx.x;   // 0..32767
  {  // kb item: (h, s, d8)
    int h = id >> 14, s = (id >> 3) & 2047, d8 = (id & 7) << 3;
    const float4* gp = (const float4*)(k + ((size_t)s * HKV + h) * DH + d8);
    float4 a = gp[0], b = gp[1];
    union { uint4 qv; u16 u[8]; } P;
    P.u[0]=f2bf(a.x); P.u[1]=f2bf(a.y); P.u[2]=f2bf(a.z); P.u[3]=f2bf(a.w);
    P.u[4]=f2bf(b.x); P.u[5]=f2bf(b.y); P.u[6]=f2bf(b.z); P.u[7]=f2bf(b.w);
    *(uint4*)(kb + ((size_t)h * S_LEN + s) * 64 + (d8 ^ ((s & 7) << 3))) = P.qv;
  }
  {  // vt item: (h, d, s8)
    int h = id >> 14, d = (id >> 8) & 63, s8 = (id & 255) << 3;
    union { uint4 qv; u16 u[8]; } P;
    #pragma unroll
    for (int j = 0; j < 8; ++j)
      P.u[j] = f2bf(v[(size_t)(s8 + j) * (HKV * DH) + h * DH + d]);
    int dst = (s8 & ~63) | ((s8 & 63) ^ ((d & 7) << 3));
    *(uint4*)(vt + ((size_t)h * 64 + d) * S_LEN + dst) = P.qv;
  }
  {  // gates[s][hq][e]
    int s = id >> 4, hq = id & 15;
    const float4* qp = (const float4*)(q + ((size_t)s * HQ + hq) * DH);
    const float4* w0 = (const float4*)(wg);
    const float4* w1 = (const float4*)(wg + DH);
    const float4* w2 = (const float4*)(wg + 2 * DH);
    float g0 = 0.f, g1 = 0.f, g2 = 0.f;
    #pragma unroll
    for (int i = 0; i < 16; ++i) {
      float4 a = qp[i];
      float4 b0 = w0[i], b1 = w1[i], b2 = w2[i];
      g0 += a.x*b0.x + a.y*b0.y + a.z*b0.z + a.w*b0.w;
      g1 += a.x*b1.x + a.y*b1.y + a.z*b1.z + a.w*b1.w;
      g2 += a.x*b2.x + a.y*b2.y + a.z*b2.z + a.w*b2.w;
    }
    float* gp = gates + ((size_t)s * HQ + hq) * 3;
    gp[0] = g0; gp[1] = g1; gp[2] = g2;
  }
}

// ---- Stage B v3: wave-per-query compressed attn + pooling + exact top-8 ----
// blockIdx low bit = h (load-balance: CU's resident blocks span distant s-tiles)
__global__ __launch_bounds__(256) void nsa_cmp_kernel(
    const float* __restrict__ q, const float* __restrict__ ck,
    const float* __restrict__ cv, const float* __restrict__ gates,
    float* __restrict__ out, int* __restrict__ sel) {
  int h  = blockIdx.x & 1;
  int s0 = (blockIdx.x >> 1) << 2;   // 4 queries, one per wave
  int tid = threadIdx.x;
  int w = tid >> 6, l = tid & 63;
  __shared__ float t4s[SC * DH];       // K (swizzled), then V (plain)
  __shared__ float pbuf[4][GQ][136];
  __shared__ float pkvb[4][128];
  float4* t4 = (float4*)t4s;

  int s  = s0 + w;
  int hq = l >> 3, cg = l & 7;

  {
    const float4* ck4 = (const float4*)(ck + (size_t)h * SC * DH);
    for (int f = tid; f < SC * 16; f += 256) {
      int c = f >> 4, i = f & 15;
      t4[(c << 4) | (i ^ (c & 7))] = ck4[f];
    }
  }
  float4 q4[16];
  {
    const float4* qp = (const float4*)(q + ((size_t)s * HQ + h * GQ + hq) * DH);
    #pragma unroll
    for (int i = 0; i < 16; ++i) q4[i] = qp[i];
  }
  __syncthreads();

  int nc = (s >= LCC - 1) ? ((s - (LCC - 1)) >> 4) + 1 : 0;

  float p[16];
  float m = -INFINITY;
  #pragma unroll
  for (int t = 0; t < 16; ++t) {
    int c = cg + (t << 3);
    float d = 0.f;
    #pragma unroll
    for (int i = 0; i < 16; ++i) {
      float4 kk = t4[(c << 4) | (i ^ cg)];
      d = fmaf(kk.x, q4[i].x, d); d = fmaf(kk.y, q4[i].y, d);
      d = fmaf(kk.z, q4[i].z, d); d = fmaf(kk.w, q4[i].w, d);
    }
    float x = (c < nc) ? d * SCALE : -INFINITY;
    p[t] = x;
    m = fmaxf(m, x);
  }
  m = fmaxf(m, __shfl_xor(m, 1));
  m = fmaxf(m, __shfl_xor(m, 2));
  m = fmaxf(m, __shfl_xor(m, 4));
  m = fmaxf(m, -1e30f);
  float ssum = 0.f;
  #pragma unroll
  for (int t = 0; t < 16; ++t) { p[t] = expf(p[t] - m); ssum += p[t]; }
  ssum += __shfl_xor(ssum, 1);
  ssum += __shfl_xor(ssum, 2);
  ssum += __shfl_xor(ssum, 4);
  float inv = 1.f / fmaxf(ssum, 1e-20f);
  #pragma unroll
  for (int t = 0; t < 16; ++t) {
    p[t] *= inv;
    pbuf[w][hq][cg + (t << 3)] = p[t];
  }
  #pragma unroll
  for (int t = 0; t < 16; ++t) {
    float v0 = p[t];
    v0 += __shfl_xor(v0, 8);
    v0 += __shfl_xor(v0, 16);
    v0 += __shfl_xor(v0, 32);
    p[t] = v0;
  }
  if (hq == 0) {
    #pragma unroll
    for (int t = 0; t < 16; ++t) pkvb[w][cg + (t << 3)] = p[t];
  }
  if (l < 32) {
    float pv;
    if (l < NOUT) {
      float tt = 0.f;
      #pragma unroll
      for (int u = 0; u < 5; ++u) tt += pkvb[w][l * 4 + u];
      pv = tt * 0.2f;
    } else pv = -1.0f;
    if (l == (s >> 6)) pv = INFINITY;
    int* dst = sel + ((size_t)h * S_LEN + s) * KSEL;
    #pragma unroll
    for (int kk = 0; kk < KSEL; ++kk) {
      float v0 = pv; int i0 = l;
      #pragma unroll
      for (int off = 16; off; off >>= 1) {
        float v1 = __shfl_xor(v0, off, 32);
        int   i1 = __shfl_xor(i0, off, 32);
        if (v1 > v0 || (v1 == v0 && i1 < i0)) { v0 = v1; i0 = i1; }
      }
      if (l == 0) dst[kk] = i0;
      if (l == i0) pv = -INFINITY;
    }
  }
  __syncthreads();
  {
    const float4* cv4 = (const float4*)(cv + (size_t)h * SC * DH);
    for (int f = tid; f < SC * 16; f += 256) t4[f] = cv4[f];
  }
  __syncthreads();
  {
    int d4 = l & 15, hg2 = l >> 4;
    float4 a0 = {0.f,0.f,0.f,0.f}, a1 = {0.f,0.f,0.f,0.f};
    #pragma unroll 2
    for (int c = 0; c < nc; ++c) {
      float4 vv = t4[(c << 4) | d4];
      float p0 = pbuf[w][hg2][c];
      float p1 = pbuf[w][hg2 + 4][c];
      a0.x = fmaf(p0, vv.x, a0.x); a0.y = fmaf(p0, vv.y, a0.y);
      a0.z = fmaf(p0, vv.z, a0.z); a0.w = fmaf(p0, vv.w, a0.w);
      a1.x = fmaf(p1, vv.x, a1.x); a1.y = fmaf(p1, vv.y, a1.y);
      a1.z = fmaf(p1, vv.z, a1.z); a1.w = fmaf(p1, vv.w, a1.w);
    }
    float g0 = gates[((size_t)s * HQ + h * GQ + hg2) * 3 + 2];
    float g1 = gates[((size_t)s * HQ + h * GQ + hg2 + 4) * 3 + 2];
    float4 o0, o1;
    o0.x = g0*a0.x; o0.y = g0*a0.y; o0.z = g0*a0.z; o0.w = g0*a0.w;
    o1.x = g1*a1.x; o1.y = g1*a1.y; o1.z = g1*a1.z; o1.w = g1*a1.w;
    ((float4*)(out + ((size_t)s * HQ + h * GQ + hg2) * DH))[d4] = o0;
    ((float4*)(out + ((size_t)s * HQ + h * GQ + hg2 + 4) * DH))[d4] = o1;
  }
}

// ---------------- selswa v3: balanced grid, exp2 softmax, DMA-staged ----------------
__device__ __forceinline__ void stage_chunk(const u16* kbh, const u16* vth,
                                            int cb, int w, int l,
                                            short* kT, short* vT) {
  #pragma unroll
  for (int r = 0; r < 2; ++r) {
    int seg = w * 2 + r;
    gl_lds16((const char*)kbh + (size_t)cb * 128 + seg * 1024 + l * 16,
             (char*)kT + seg * 1024);
    int drow = seg * 8 + (l >> 3);
    gl_lds16((const char*)vth + (size_t)drow * (S_LEN * 2) + cb * 2 + (l & 7) * 16,
             (char*)vT + seg * 1024);
  }
}

template <bool MASKED>
__device__ __forceinline__ void compute_chunk(
    const short* kT, const short* vT, short* pTw,
    int cb, int lo_l, u32 span, float selbias, int l,
    const bf16x8 (&qf)[2], f32x4 (&o)[4], float& mrun, float& lsum) {
  int col = l & 15;
  int lg8 = (l >> 4) << 3;
  int kq  = (l >> 4) << 2;
  int xr  = (l & 7) << 3;

  // ---- S^T = K · Q^T (Q pre-scaled by SCALE*log2e; scores in log2 units) ----
  f32x4 st[4];
  #pragma unroll
  for (int mt = 0; mt < 4; ++mt) st[mt] = (f32x4){0.f, 0.f, 0.f, 0.f};
  __builtin_amdgcn_s_setprio(1);
  #pragma unroll
  for (int ks = 0; ks < 2; ++ks) {
    int co = (ks * 32 + lg8) ^ xr;
    #pragma unroll
    for (int mt = 0; mt < 4; ++mt) {
      bf16x8 kf = *(const bf16x8*)(&kT[((mt * 16 + col) << 6) | co]);
      st[mt] = __builtin_amdgcn_mfma_f32_16x16x32_bf16(kf, qf[ks], st[mt], 0, 0, 0);
    }
  }
  __builtin_amdgcn_s_setprio(0);

  // ---- mask ----
  float mc = -INFINITY;
  #pragma unroll
  for (int mt = 0; mt < 4; ++mt) {
    #pragma unroll
    for (int r = 0; r < 4; ++r) {
      float x = st[mt][r] + selbias;
      if (MASKED) {
        int key = cb + mt * 16 + kq + r;
        bool vis = (u32)(key - lo_l) <= span;
        x = vis ? x : -INFINITY;
      }
      st[mt][r] = x;
      mc = fmaxf(mc, x);
    }
  }
  mc = fmaxf(mc, __shfl_xor(mc, 16));
  mc = fmaxf(mc, __shfl_xor(mc, 32));

  // ---- defer-max online softmax (T13; THR = 8*log2e ~ 11 in log2 units) ----
  if (!__all(mc <= mrun + 11.0f)) {
    float mn = fmaxf(fmaxf(mrun, mc), -1e30f);
    float fr = fexp2(mrun - mn);
    #pragma unroll
    for (int mt = 0; mt < 4; ++mt) o[mt] *= fr;
    lsum *= fr;
    mrun = mn;
  }
  float ps = 0.f;
  #pragma unroll
  for (int mt = 0; mt < 4; ++mt) {
    #pragma unroll
    for (int r = 0; r < 4; ++r) {
      float p = fexp2(st[mt][r] - mrun);
      st[mt][r] = p; ps += p;
    }
  }
  ps += __shfl_xor(ps, 16);
  ps += __shfl_xor(ps, 32);
  lsum += ps;

  // ---- P -> bf16 (cvt_pk) -> per-wave LDS ----
  int pc = col << 6;
  #pragma unroll
  for (int mt = 0; mt < 4; ++mt) {
    #pragma unroll
    for (int pr = 0; pr < 2; ++pr) {
      u32 pk;
      asm("v_cvt_pk_bf16_f32 %0, %1, %2"
          : "=v"(pk) : "v"(st[mt][pr * 2]), "v"(st[mt][pr * 2 + 1]));
      int key = mt * 16 + kq + pr * 2;
      *(u32*)(&pTw[pc | (key ^ xr)]) = pk;
    }
  }

  // ---- O^T += V^T · P ----
  __builtin_amdgcn_s_setprio(1);
  #pragma unroll
  for (int ks = 0; ks < 2; ++ks) {
    int co = (ks * 32 + lg8) ^ xr;
    bf16x8 pf = *(const bf16x8*)(&pTw[pc | co]);
    #pragma unroll
    for (int mt = 0; mt < 4; ++mt) {
      bf16x8 vf = *(const bf16x8*)(&vT[((mt * 16 + col) << 6) | co]);
      o[mt] = __builtin_amdgcn_mfma_f32_16x16x32_bf16(vf, pf, o[mt], 0, 0, 0);
    }
  }
  __builtin_amdgcn_s_setprio(0);
}

// mode 2 (combined): blockIdx = tile*4 + pass*2 + h  -> CU's 4 resident blocks
//   span tiles ~64 apart AND both passes: flattens the causal work ramp.
// mode 0/1 (fallback): blockIdx = tile*2 + h.
__global__ __launch_bounds__(256) void nsa_selswa_kernel(
    const float* __restrict__ q, const u16* __restrict__ kb,
    const u16* __restrict__ vt, const float* __restrict__ gates,
    const int* __restrict__ sel, float* __restrict__ out,
    float* __restrict__ osel, int mode) {
  int bid = blockIdx.x;
  int pass, h, tile;
  if (mode == 2) { tile = bid >> 2; pass = (bid >> 1) & 1; h = bid & 1; }
  else           { tile = bid >> 1; pass = mode;           h = bid & 1; }
  int s0 = tile * QTS;
  int b0 = s0 >> 6;
  int tid = threadIdx.x;
  int w = tid >> 6, l = tid & 63;
  __shared__ __align__(16) short kTb[2][64 * 64];
  __shared__ __align__(16) short vTb[2][64 * 64];
  __shared__ __align__(16) short pT[4][16 * 64];   // selsh aliased below
  int* selsh = (int*)&pT[0][0];

  if (tid < 64)
    selsh[tid] = sel[((size_t)h * S_LEN + s0 + (tid >> 3)) * KSEL + (tid & 7)];

  int col = l & 15, qq = col & 7, gh2 = col >> 3;
  int s_lane = s0 + qq;
  size_t qrow = (size_t)s_lane * HQ + h * 8 + w * 2 + gh2;

  bf16x8 qf[2];   // Q pre-scaled by SCALE*log2e
  #pragma unroll
  for (int ks = 0; ks < 2; ++ks) {
    const float4* gp = (const float4*)(q + qrow * DH + ks * 32 + ((l >> 4) << 3));
    float4 a = gp[0], b = gp[1];
    union { bf16x8 v; u16 u[8]; } P;
    P.u[0]=f2bf(a.x*QSC); P.u[1]=f2bf(a.y*QSC); P.u[2]=f2bf(a.z*QSC); P.u[3]=f2bf(a.w*QSC);
    P.u[4]=f2bf(b.x*QSC); P.u[5]=f2bf(b.y*QSC); P.u[6]=f2bf(b.z*QSC); P.u[7]=f2bf(b.w*QSC);
    qf[ks] = P.v;
  }
  float gate = gates[qrow * 3 + (pass ? 1 : 0)];
  __syncthreads();

  u32 qmask = 0;
  #pragma unroll
  for (int j = 0; j < 8; ++j) qmask |= 1u << selsh[qq * 8 + j];

  const u16* kbh = kb + (size_t)h * S_LEN * 64;
  const u16* vth = vt + (size_t)h * 64 * S_LEN;
  short* pTw = pT[w];

  f32x4 o[4];
  #pragma unroll
  for (int mt = 0; mt < 4; ++mt) o[mt] = (f32x4){0.f, 0.f, 0.f, 0.f};
  float mrun = -INFINITY, lsum = 0.f;

  if (pass == 0) {
    // ---- SEL: union of selected causal blocks ----
    u32 un = qmask;
    un |= (u32)__shfl_xor((int)un, 1);
    un |= (u32)__shfl_xor((int)un, 2);
    un |= (u32)__shfl_xor((int)un, 4);
    un &= (2u << b0) - 1;              // drop phantom blocks beyond causal
    u32 rem = un;
    int cb = __builtin_ctz(rem) << 6;
    int par = 0;
    stage_chunk(kbh, vth, cb, w, l, kTb[0], vTb[0]);
    __syncthreads();
    while (1) {
      u32 rem2 = rem & (rem - 1);
      int cbn = rem2 ? (__builtin_ctz(rem2) << 6) : -1;
      if (cbn >= 0) stage_chunk(kbh, vth, cbn, w, l, kTb[par ^ 1], vTb[par ^ 1]);
      float selbias = ((qmask >> (cb >> 6)) & 1) ? 0.f : -INFINITY;
      if (cb == b0 * 64)
        compute_chunk<true>(kTb[par], vTb[par], pTw, cb, 0, (u32)s_lane,
                            selbias, l, qf, o, mrun, lsum);
      else
        compute_chunk<false>(kTb[par], vTb[par], pTw, cb, 0, 0,
                             selbias, l, qf, o, mrun, lsum);
      __syncthreads();
      if (cbn < 0) break;
      rem = rem2; cb = cbn; par ^= 1;
    }
  } else {
    // ---- SWA ----
    int t0 = s0 - (WIN - 1); if (t0 < 0) t0 = 0;
    int lo_l = s_lane - (WIN - 1);
    int cb = t0 & ~63;
    int cbt = b0 * 64;
    int par = 0;
    stage_chunk(kbh, vth, cb, w, l, kTb[0], vTb[0]);
    __syncthreads();
    while (1) {
      int cbn = (cb < cbt) ? cb + 64 : -1;
      if (cbn >= 0) stage_chunk(kbh, vth, cbn, w, l, kTb[par ^ 1], vTb[par ^ 1]);
      if ((cb + 504 < s0) || (cb == cbt))
        compute_chunk<true>(kTb[par], vTb[par], pTw, cb, lo_l, (u32)(WIN - 1),
                            0.f, l, qf, o, mrun, lsum);
      else
        compute_chunk<false>(kTb[par], vTb[par], pTw, cb, 0, 0,
                             0.f, l, qf, o, mrun, lsum);
      __syncthreads();
      if (cbn < 0) break;
      cb = cbn; par ^= 1;
    }
  }

  float gv = gate / fmaxf(lsum, 1e-20f);
  int kq = (l >> 4) << 2;
  if (mode == 2 && pass == 0) {
    #pragma unroll
    for (int mt = 0; mt < 4; ++mt) {
      float4 pv;
      pv.x = gv * o[mt][0]; pv.y = gv * o[mt][1];
      pv.z = gv * o[mt][2]; pv.w = gv * o[mt][3];
      *(float4*)(osel + qrow * DH + mt * 16 + kq) = pv;
    }
  } else {
    #pragma unroll
    for (int mt = 0; mt < 4; ++mt) {
      float4* op = (float4*)(out + qrow * DH + mt * 16 + kq);
      float4 pv = *op;
      pv.x = fmaf(gv, o[mt][0], pv.x); pv.y = fmaf(gv, o[mt][1], pv.y);
      pv.z = fmaf(gv, o[mt][2], pv.z); pv.w = fmaf(gv, o[mt][3], pv.w);
      *op = pv;
    }
  }
}

__global__ __launch_bounds__(256) void nsa_merge_kernel(
    const float* __restrict__ osel, float* __restrict__ out) {
  int i = blockIdx.x * 256 + threadIdx.x;
  float4 a = ((const float4*)osel)[i];
  float4 b = ((float4*)out)[i];
  b.x += a.x; b.y += a.y; b.z += a.z; b.w += a.w;
  ((float4*)out)[i] = b;
}

extern "C" void kernel_launch(void* const* d_in, const int* in_sizes, int n_in,
                              void* d_out, int out_size, void* d_ws, size_t ws_size,
                              hipStream_t stream) {
  const float* q  = (const float*)d_in[0];
  const float* k  = (const float*)d_in[1];
  const float* v  = (const float*)d_in[2];
  const float* wk = (const float*)d_in[3];
  const float* wv = (const float*)d_in[4];
  const float* wg = (const float*)d_in[5];
  float* out = (float*)d_out;

  float* ck    = (float*)d_ws;                               // 16256 f
  float* cv    = ck + (size_t)HKV * SC * DH;                 // 16256 f
  float* gates = cv + (size_t)HKV * SC * DH;                 // 98304 f
  int*   sel   = (int*)(gates + (size_t)S_LEN * HQ * 3);     // 32768 i
  u16*   kb    = (u16*)(sel + (size_t)HKV * S_LEN * KSEL);   // 262144 u16
  u16*   vt    = kb + (size_t)HKV * S_LEN * DH;              // 262144 u16
  float* osel  = (float*)(vt + (size_t)HKV * DH * S_LEN);    // 2097152 f
  size_t need  = (size_t)((char*)(osel + (size_t)S_LEN * HQ * DH) - (char*)d_ws);

  nsa_conv_kernel<<<HKV * SC, 256, 0, stream>>>(k, v, wk, wv, ck, cv);
  nsa_prep_kernel<<<128, 256, 0, stream>>>(q, k, v, wg, kb, vt, gates);
  nsa_cmp_kernel<<<HKV * (S_LEN / 4), 256, 0, stream>>>(q, ck, cv, gates, out, sel);
  if (ws_size >= need) {
    nsa_selswa_kernel<<<2 * HKV * 256, 256, 0, stream>>>(q, kb, vt, gates, sel, out, osel, 2);
    nsa_merge_kernel<<<(S_LEN * HQ * DH / 4) / 256, 256, 0, stream>>>(osel, out);
  } else {
    nsa_selswa_kernel<<<HKV * 256, 256, 0, stream>>>(q, kb, vt, gates, sel, out, osel, 0);
    nsa_selswa_kernel<<<HKV * 256, 256, 0, stream>>>(q, kb, vt, gates, sel, out, osel, 1);
  }
}

// Round 12
// 188.797 us; speedup vs baseline: 1.0860x; 1.0860x over previous
//
#include <hip/hip_runtime.h>
#include <hip/hip_bf16.h>
#include <math.h>

#define S_LEN  2048
#define HQ     16
#define HKV    2
#define GQ     8      // Hq / Hkv
#define DH     64
#define LCC    32     // compression block
#define CSTRIDE 16
#define SC     127    // (S - LC)/STRIDE + 1
#define LB     64     // selection block
#define KSEL   8
#define WIN    512
#define NB     32     // S / LB
#define NOUT   31     // pooled length before pad
#define QTS    8      // queries per block in selswa kernel
#define SCALE  0.125f
#define QSC    (0.125f * 1.4426950408889634f)   // SCALE * log2(e): exp2-domain scores

typedef __attribute__((ext_vector_type(8))) short bf16x8;
typedef __attribute__((ext_vector_type(4))) float f32x4;
typedef unsigned short u16;
typedef unsigned int   u32;

__device__ __forceinline__ u16 f2bf(float f) {
  u32 u = __float_as_uint(f);
  return (u16)((u + 0x7FFFu + ((u >> 16) & 1u)) >> 16);
}

__device__ __forceinline__ float fexp2(float x) {
  float r;
  asm("v_exp_f32 %0, %1" : "=v"(r) : "v"(x));
  return r;
}

__device__ __forceinline__ void gl_lds16(const void* g, void* lds) {
  __builtin_amdgcn_global_load_lds(
      (const __attribute__((address_space(1))) void*)g,
      (__attribute__((address_space(3))) void*)lds, 16, 0, 0);
}

// ---------------- Stage A: conv1d compression (split-K, 256 thr) ----------------
__global__ __launch_bounds__(256) void nsa_conv_kernel(
    const float* __restrict__ k, const float* __restrict__ v,
    const float* __restrict__ wk, const float* __restrict__ wv,
    float* __restrict__ ck, float* __restrict__ cv) {
  int c = blockIdx.x % SC;
  int h = blockIdx.x / SC;
  __shared__ float kin[LCC * DH];
  __shared__ float vin[LCC * DH];
  __shared__ float cred[128];
  int tid = threadIdx.x;
  for (int f = tid; f < LCC * DH / 4; f += 256) {
    int tt = f >> 4, i4 = f & 15;
    int row = c * CSTRIDE + tt;
    ((float4*)kin)[f] = ((const float4*)(k + ((size_t)row * HKV + h) * DH))[i4];
    ((float4*)vin)[f] = ((const float4*)(v + ((size_t)row * HKV + h) * DH))[i4];
  }
  __syncthreads();
  int o  = tid & 63;
  int kv = (tid >> 6) & 1;   // 0:k 1:v
  int uh = tid >> 7;         // u half
  const float* w  = (kv ? wv : wk) + (size_t)o * (DH * LCC) + uh * 16;
  const float* in = (kv ? vin : kin) + uh * 16 * DH;
  float acc = 0.f;
  for (int i = 0; i < DH; ++i) {
    #pragma unroll
    for (int u = 0; u < 16; ++u)
      acc = fmaf(in[u * DH + i], w[i * LCC + u], acc);
  }
  if (uh == 1) cred[tid & 127] = acc;
  __syncthreads();
  if (uh == 0) {
    acc += cred[tid & 127];
    float* dst = (kv ? cv : ck);
    dst[((size_t)h * SC + c) * DH + o] = acc;
  }
}

// ---- prep: pre-swizzled bf16 K + V^T (for global_load_lds staging) + gates ----
__global__ __launch_bounds__(256) void nsa_prep_kernel(
    const float* __restrict__ q, const float* __restrict__ k,
    const float* __restrict__ v, const float* __restrict__ wg,
    u16* __restrict__ kb, u16* __restrict__ vt, float* __restrict__ gates) {
  int id = blockIdx.x * 256 + threadIdx.x;   // 0..32767
  {  // kb item: (h, s, d8)
    int h = id >> 14, s = (id >> 3) & 2047, d8 = (id & 7) << 3;
    const float4* gp = (const float4*)(k + ((size_t)s * HKV + h) * DH + d8);
    float4 a = gp[0], b = gp[1];
    union { uint4 qv; u16 u[8]; } P;
    P.u[0]=f2bf(a.x); P.u[1]=f2bf(a.y); P.u[2]=f2bf(a.z); P.u[3]=f2bf(a.w);
    P.u[4]=f2bf(b.x); P.u[5]=f2bf(b.y); P.u[6]=f2bf(b.z); P.u[7]=f2bf(b.w);
    *(uint4*)(kb + ((size_t)h * S_LEN + s) * 64 + (d8 ^ ((s & 7) << 3))) = P.qv;
  }
  {  // vt item: (h, d, s8)
    int h = id >> 14, d = (id >> 8) & 63, s8 = (id & 255) << 3;
    union { uint4 qv; u16 u[8]; } P;
    #pragma unroll
    for (int j = 0; j < 8; ++j)
      P.u[j] = f2bf(v[(size_t)(s8 + j) * (HKV * DH) + h * DH + d]);
    int dst = (s8 & ~63) | ((s8 & 63) ^ ((d & 7) << 3));
    *(uint4*)(vt + ((size_t)h * 64 + d) * S_LEN + dst) = P.qv;
  }
  {  // gates[s][hq][e]
    int s = id >> 4, hq = id & 15;
    const float4* qp = (const float4*)(q + ((size_t)s * HQ + hq) * DH);
    const float4* w0 = (const float4*)(wg);
    const float4* w1 = (const float4*)(wg + DH);
    const float4* w2 = (const float4*)(wg + 2 * DH);
    float g0 = 0.f, g1 = 0.f, g2 = 0.f;
    #pragma unroll
    for (int i = 0; i < 16; ++i) {
      float4 a = qp[i];
      float4 b0 = w0[i], b1 = w1[i], b2 = w2[i];
      g0 += a.x*b0.x + a.y*b0.y + a.z*b0.z + a.w*b0.w;
      g1 += a.x*b1.x + a.y*b1.y + a.z*b1.z + a.w*b1.w;
      g2 += a.x*b2.x + a.y*b2.y + a.z*b2.z + a.w*b2.w;
    }
    float* gp = gates + ((size_t)s * HQ + hq) * 3;
    gp[0] = g0; gp[1] = g1; gp[2] = g2;
  }
}

// ---- Stage B v3: wave-per-query compressed attn + pooling + exact top-8 ----
// round-7 mapping: h in HIGH bits (tile-contiguous dispatch = L2 locality)
__global__ __launch_bounds__(256) void nsa_cmp_kernel(
    const float* __restrict__ q, const float* __restrict__ ck,
    const float* __restrict__ cv, const float* __restrict__ gates,
    float* __restrict__ out, int* __restrict__ sel) {
  int h  = blockIdx.x >> 9;          // / 512
  int s0 = (blockIdx.x & 511) << 2;  // 4 queries, one per wave
  int tid = threadIdx.x;
  int w = tid >> 6, l = tid & 63;
  __shared__ float t4s[SC * DH];       // K (swizzled), then V (plain)
  __shared__ float pbuf[4][GQ][136];
  __shared__ float pkvb[4][128];
  float4* t4 = (float4*)t4s;

  int s  = s0 + w;
  int hq = l >> 3, cg = l & 7;

  {
    const float4* ck4 = (const float4*)(ck + (size_t)h * SC * DH);
    for (int f = tid; f < SC * 16; f += 256) {
      int c = f >> 4, i = f & 15;
      t4[(c << 4) | (i ^ (c & 7))] = ck4[f];
    }
  }
  float4 q4[16];
  {
    const float4* qp = (const float4*)(q + ((size_t)s * HQ + h * GQ + hq) * DH);
    #pragma unroll
    for (int i = 0; i < 16; ++i) q4[i] = qp[i];
  }
  __syncthreads();

  int nc = (s >= LCC - 1) ? ((s - (LCC - 1)) >> 4) + 1 : 0;

  float p[16];
  float m = -INFINITY;
  #pragma unroll
  for (int t = 0; t < 16; ++t) {
    int c = cg + (t << 3);
    float d = 0.f;
    #pragma unroll
    for (int i = 0; i < 16; ++i) {
      float4 kk = t4[(c << 4) | (i ^ cg)];
      d = fmaf(kk.x, q4[i].x, d); d = fmaf(kk.y, q4[i].y, d);
      d = fmaf(kk.z, q4[i].z, d); d = fmaf(kk.w, q4[i].w, d);
    }
    float x = (c < nc) ? d * SCALE : -INFINITY;
    p[t] = x;
    m = fmaxf(m, x);
  }
  m = fmaxf(m, __shfl_xor(m, 1));
  m = fmaxf(m, __shfl_xor(m, 2));
  m = fmaxf(m, __shfl_xor(m, 4));
  m = fmaxf(m, -1e30f);
  float ssum = 0.f;
  #pragma unroll
  for (int t = 0; t < 16; ++t) { p[t] = expf(p[t] - m); ssum += p[t]; }
  ssum += __shfl_xor(ssum, 1);
  ssum += __shfl_xor(ssum, 2);
  ssum += __shfl_xor(ssum, 4);
  float inv = 1.f / fmaxf(ssum, 1e-20f);
  #pragma unroll
  for (int t = 0; t < 16; ++t) {
    p[t] *= inv;
    pbuf[w][hq][cg + (t << 3)] = p[t];
  }
  #pragma unroll
  for (int t = 0; t < 16; ++t) {
    float v0 = p[t];
    v0 += __shfl_xor(v0, 8);
    v0 += __shfl_xor(v0, 16);
    v0 += __shfl_xor(v0, 32);
    p[t] = v0;
  }
  if (hq == 0) {
    #pragma unroll
    for (int t = 0; t < 16; ++t) pkvb[w][cg + (t << 3)] = p[t];
  }
  if (l < 32) {
    float pv;
    if (l < NOUT) {
      float tt = 0.f;
      #pragma unroll
      for (int u = 0; u < 5; ++u) tt += pkvb[w][l * 4 + u];
      pv = tt * 0.2f;
    } else pv = -1.0f;
    if (l == (s >> 6)) pv = INFINITY;
    int* dst = sel + ((size_t)h * S_LEN + s) * KSEL;
    #pragma unroll
    for (int kk = 0; kk < KSEL; ++kk) {
      float v0 = pv; int i0 = l;
      #pragma unroll
      for (int off = 16; off; off >>= 1) {
        float v1 = __shfl_xor(v0, off, 32);
        int   i1 = __shfl_xor(i0, off, 32);
        if (v1 > v0 || (v1 == v0 && i1 < i0)) { v0 = v1; i0 = i1; }
      }
      if (l == 0) dst[kk] = i0;
      if (l == i0) pv = -INFINITY;
    }
  }
  __syncthreads();
  {
    const float4* cv4 = (const float4*)(cv + (size_t)h * SC * DH);
    for (int f = tid; f < SC * 16; f += 256) t4[f] = cv4[f];
  }
  __syncthreads();
  {
    int d4 = l & 15, hg2 = l >> 4;
    float4 a0 = {0.f,0.f,0.f,0.f}, a1 = {0.f,0.f,0.f,0.f};
    #pragma unroll 2
    for (int c = 0; c < nc; ++c) {
      float4 vv = t4[(c << 4) | d4];
      float p0 = pbuf[w][hg2][c];
      float p1 = pbuf[w][hg2 + 4][c];
      a0.x = fmaf(p0, vv.x, a0.x); a0.y = fmaf(p0, vv.y, a0.y);
      a0.z = fmaf(p0, vv.z, a0.z); a0.w = fmaf(p0, vv.w, a0.w);
      a1.x = fmaf(p1, vv.x, a1.x); a1.y = fmaf(p1, vv.y, a1.y);
      a1.z = fmaf(p1, vv.z, a1.z); a1.w = fmaf(p1, vv.w, a1.w);
    }
    float g0 = gates[((size_t)s * HQ + h * GQ + hg2) * 3 + 2];
    float g1 = gates[((size_t)s * HQ + h * GQ + hg2 + 4) * 3 + 2];
    float4 o0, o1;
    o0.x = g0*a0.x; o0.y = g0*a0.y; o0.z = g0*a0.z; o0.w = g0*a0.w;
    o1.x = g1*a1.x; o1.y = g1*a1.y; o1.z = g1*a1.z; o1.w = g1*a1.w;
    ((float4*)(out + ((size_t)s * HQ + h * GQ + hg2) * DH))[d4] = o0;
    ((float4*)(out + ((size_t)s * HQ + h * GQ + hg2 + 4) * DH))[d4] = o1;
  }
}

// ---------------- selswa: round-7 grid (L2-local), exp2 softmax, DMA-staged ----------------
__device__ __forceinline__ void stage_chunk(const u16* kbh, const u16* vth,
                                            int cb, int w, int l,
                                            short* kT, short* vT) {
  #pragma unroll
  for (int r = 0; r < 2; ++r) {
    int seg = w * 2 + r;
    gl_lds16((const char*)kbh + (size_t)cb * 128 + seg * 1024 + l * 16,
             (char*)kT + seg * 1024);
    int drow = seg * 8 + (l >> 3);
    gl_lds16((const char*)vth + (size_t)drow * (S_LEN * 2) + cb * 2 + (l & 7) * 16,
             (char*)vT + seg * 1024);
  }
}

template <bool MASKED>
__device__ __forceinline__ void compute_chunk(
    const short* kT, const short* vT, short* pTw,
    int cb, int lo_l, u32 span, float selbias, int l,
    const bf16x8 (&qf)[2], f32x4 (&o)[4], float& mrun, float& lsum) {
  int col = l & 15;
  int lg8 = (l >> 4) << 3;
  int kq  = (l >> 4) << 2;
  int xr  = (l & 7) << 3;

  // ---- S^T = K · Q^T (Q pre-scaled by SCALE*log2e; scores in log2 units) ----
  f32x4 st[4];
  #pragma unroll
  for (int mt = 0; mt < 4; ++mt) st[mt] = (f32x4){0.f, 0.f, 0.f, 0.f};
  __builtin_amdgcn_s_setprio(1);
  #pragma unroll
  for (int ks = 0; ks < 2; ++ks) {
    int co = (ks * 32 + lg8) ^ xr;
    #pragma unroll
    for (int mt = 0; mt < 4; ++mt) {
      bf16x8 kf = *(const bf16x8*)(&kT[((mt * 16 + col) << 6) | co]);
      st[mt] = __builtin_amdgcn_mfma_f32_16x16x32_bf16(kf, qf[ks], st[mt], 0, 0, 0);
    }
  }
  __builtin_amdgcn_s_setprio(0);

  // ---- mask ----
  float mc = -INFINITY;
  #pragma unroll
  for (int mt = 0; mt < 4; ++mt) {
    #pragma unroll
    for (int r = 0; r < 4; ++r) {
      float x = st[mt][r] + selbias;
      if (MASKED) {
        int key = cb + mt * 16 + kq + r;
        bool vis = (u32)(key - lo_l) <= span;
        x = vis ? x : -INFINITY;
      }
      st[mt][r] = x;
      mc = fmaxf(mc, x);
    }
  }
  mc = fmaxf(mc, __shfl_xor(mc, 16));
  mc = fmaxf(mc, __shfl_xor(mc, 32));

  // ---- defer-max online softmax (T13; THR = 8*log2e ~ 11 in log2 units) ----
  if (!__all(mc <= mrun + 11.0f)) {
    float mn = fmaxf(fmaxf(mrun, mc), -1e30f);
    float fr = fexp2(mrun - mn);
    #pragma unroll
    for (int mt = 0; mt < 4; ++mt) o[mt] *= fr;
    lsum *= fr;
    mrun = mn;
  }
  float ps = 0.f;
  #pragma unroll
  for (int mt = 0; mt < 4; ++mt) {
    #pragma unroll
    for (int r = 0; r < 4; ++r) {
      float p = fexp2(st[mt][r] - mrun);
      st[mt][r] = p; ps += p;
    }
  }
  ps += __shfl_xor(ps, 16);
  ps += __shfl_xor(ps, 32);
  lsum += ps;

  // ---- P -> bf16 (cvt_pk) -> per-wave LDS ----
  int pc = col << 6;
  #pragma unroll
  for (int mt = 0; mt < 4; ++mt) {
    #pragma unroll
    for (int pr = 0; pr < 2; ++pr) {
      u32 pk;
      asm("v_cvt_pk_bf16_f32 %0, %1, %2"
          : "=v"(pk) : "v"(st[mt][pr * 2]), "v"(st[mt][pr * 2 + 1]));
      int key = mt * 16 + kq + pr * 2;
      *(u32*)(&pTw[pc | (key ^ xr)]) = pk;
    }
  }

  // ---- O^T += V^T · P ----
  __builtin_amdgcn_s_setprio(1);
  #pragma unroll
  for (int ks = 0; ks < 2; ++ks) {
    int co = (ks * 32 + lg8) ^ xr;
    bf16x8 pf = *(const bf16x8*)(&pTw[pc | co]);
    #pragma unroll
    for (int mt = 0; mt < 4; ++mt) {
      bf16x8 vf = *(const bf16x8*)(&vT[((mt * 16 + col) << 6) | co]);
      o[mt] = __builtin_amdgcn_mfma_f32_16x16x32_bf16(vf, pf, o[mt], 0, 0, 0);
    }
  }
  __builtin_amdgcn_s_setprio(0);
}

// mode 2 (combined): pass = bid >= HKV*256 (high bit), h = mid bit, tile = low
//   bits — consecutive blocks = consecutive tiles of the same (pass,h):
//   measured-good L2 locality (round-7 config, 48.5 us).
__global__ __launch_bounds__(256) void nsa_selswa_kernel(
    const float* __restrict__ q, const u16* __restrict__ kb,
    const u16* __restrict__ vt, const float* __restrict__ gates,
    const int* __restrict__ sel, float* __restrict__ out,
    float* __restrict__ osel, int mode) {
  int bid = blockIdx.x;
  int pass, rest;
  if (mode == 2) { pass = bid >= HKV * 256; rest = bid & (HKV * 256 - 1); }
  else           { pass = mode; rest = bid; }
  int h  = rest >> 8;
  int s0 = (rest & 255) * QTS;
  int b0 = s0 >> 6;
  int tid = threadIdx.x;
  int w = tid >> 6, l = tid & 63;
  __shared__ __align__(16) short kTb[2][64 * 64];
  __shared__ __align__(16) short vTb[2][64 * 64];
  __shared__ __align__(16) short pT[4][16 * 64];   // selsh aliased below
  int* selsh = (int*)&pT[0][0];

  if (tid < 64)
    selsh[tid] = sel[((size_t)h * S_LEN + s0 + (tid >> 3)) * KSEL + (tid & 7)];

  int col = l & 15, qq = col & 7, gh2 = col >> 3;
  int s_lane = s0 + qq;
  size_t qrow = (size_t)s_lane * HQ + h * 8 + w * 2 + gh2;

  bf16x8 qf[2];   // Q pre-scaled by SCALE*log2e
  #pragma unroll
  for (int ks = 0; ks < 2; ++ks) {
    const float4* gp = (const float4*)(q + qrow * DH + ks * 32 + ((l >> 4) << 3));
    float4 a = gp[0], b = gp[1];
    union { bf16x8 v; u16 u[8]; } P;
    P.u[0]=f2bf(a.x*QSC); P.u[1]=f2bf(a.y*QSC); P.u[2]=f2bf(a.z*QSC); P.u[3]=f2bf(a.w*QSC);
    P.u[4]=f2bf(b.x*QSC); P.u[5]=f2bf(b.y*QSC); P.u[6]=f2bf(b.z*QSC); P.u[7]=f2bf(b.w*QSC);
    qf[ks] = P.v;
  }
  float gate = gates[qrow * 3 + (pass ? 1 : 0)];
  __syncthreads();

  u32 qmask = 0;
  #pragma unroll
  for (int j = 0; j < 8; ++j) qmask |= 1u << selsh[qq * 8 + j];

  const u16* kbh = kb + (size_t)h * S_LEN * 64;
  const u16* vth = vt + (size_t)h * 64 * S_LEN;
  short* pTw = pT[w];

  f32x4 o[4];
  #pragma unroll
  for (int mt = 0; mt < 4; ++mt) o[mt] = (f32x4){0.f, 0.f, 0.f, 0.f};
  float mrun = -INFINITY, lsum = 0.f;

  if (pass == 0) {
    // ---- SEL: union of selected causal blocks ----
    u32 un = qmask;
    un |= (u32)__shfl_xor((int)un, 1);
    un |= (u32)__shfl_xor((int)un, 2);
    un |= (u32)__shfl_xor((int)un, 4);
    un &= (2u << b0) - 1;              // drop phantom blocks beyond causal
    u32 rem = un;
    int cb = __builtin_ctz(rem) << 6;
    int par = 0;
    stage_chunk(kbh, vth, cb, w, l, kTb[0], vTb[0]);
    __syncthreads();
    while (1) {
      u32 rem2 = rem & (rem - 1);
      int cbn = rem2 ? (__builtin_ctz(rem2) << 6) : -1;
      if (cbn >= 0) stage_chunk(kbh, vth, cbn, w, l, kTb[par ^ 1], vTb[par ^ 1]);
      float selbias = ((qmask >> (cb >> 6)) & 1) ? 0.f : -INFINITY;
      if (cb == b0 * 64)
        compute_chunk<true>(kTb[par], vTb[par], pTw, cb, 0, (u32)s_lane,
                            selbias, l, qf, o, mrun, lsum);
      else
        compute_chunk<false>(kTb[par], vTb[par], pTw, cb, 0, 0,
                             selbias, l, qf, o, mrun, lsum);
      __syncthreads();
      if (cbn < 0) break;
      rem = rem2; cb = cbn; par ^= 1;
    }
  } else {
    // ---- SWA ----
    int t0 = s0 - (WIN - 1); if (t0 < 0) t0 = 0;
    int lo_l = s_lane - (WIN - 1);
    int cb = t0 & ~63;
    int cbt = b0 * 64;
    int par = 0;
    stage_chunk(kbh, vth, cb, w, l, kTb[0], vTb[0]);
    __syncthreads();
    while (1) {
      int cbn = (cb < cbt) ? cb + 64 : -1;
      if (cbn >= 0) stage_chunk(kbh, vth, cbn, w, l, kTb[par ^ 1], vTb[par ^ 1]);
      if ((cb + 504 < s0) || (cb == cbt))
        compute_chunk<true>(kTb[par], vTb[par], pTw, cb, lo_l, (u32)(WIN - 1),
                            0.f, l, qf, o, mrun, lsum);
      else
        compute_chunk<false>(kTb[par], vTb[par], pTw, cb, 0, 0,
                             0.f, l, qf, o, mrun, lsum);
      __syncthreads();
      if (cbn < 0) break;
      cb = cbn; par ^= 1;
    }
  }

  float gv = gate / fmaxf(lsum, 1e-20f);
  int kq = (l >> 4) << 2;
  if (mode == 2 && pass == 0) {
    #pragma unroll
    for (int mt = 0; mt < 4; ++mt) {
      float4 pv;
      pv.x = gv * o[mt][0]; pv.y = gv * o[mt][1];
      pv.z = gv * o[mt][2]; pv.w = gv * o[mt][3];
      *(float4*)(osel + qrow * DH + mt * 16 + kq) = pv;
    }
  } else {
    #pragma unroll
    for (int mt = 0; mt < 4; ++mt) {
      float4* op = (float4*)(out + qrow * DH + mt * 16 + kq);
      float4 pv = *op;
      pv.x = fmaf(gv, o[mt][0], pv.x); pv.y = fmaf(gv, o[mt][1], pv.y);
      pv.z = fmaf(gv, o[mt][2], pv.z); pv.w = fmaf(gv, o[mt][3], pv.w);
      *op = pv;
    }
  }
}

__global__ __launch_bounds__(256) void nsa_merge_kernel(
    const float* __restrict__ osel, float* __restrict__ out) {
  int i = blockIdx.x * 256 + threadIdx.x;
  float4 a = ((const float4*)osel)[i];
  float4 b = ((float4*)out)[i];
  b.x += a.x; b.y += a.y; b.z += a.z; b.w += a.w;
  ((float4*)out)[i] = b;
}

extern "C" void kernel_launch(void* const* d_in, const int* in_sizes, int n_in,
                              void* d_out, int out_size, void* d_ws, size_t ws_size,
                              hipStream_t stream) {
  const float* q  = (const float*)d_in[0];
  const float* k  = (const float*)d_in[1];
  const float* v  = (const float*)d_in[2];
  const float* wk = (const float*)d_in[3];
  const float* wv = (const float*)d_in[4];
  const float* wg = (const float*)d_in[5];
  float* out = (float*)d_out;

  float* ck    = (float*)d_ws;                               // 16256 f
  float* cv    = ck + (size_t)HKV * SC * DH;                 // 16256 f
  float* gates = cv + (size_t)HKV * SC * DH;                 // 98304 f
  int*   sel   = (int*)(gates + (size_t)S_LEN * HQ * 3);     // 32768 i
  u16*   kb    = (u16*)(sel + (size_t)HKV * S_LEN * KSEL);   // 262144 u16
  u16*   vt    = kb + (size_t)HKV * S_LEN * DH;              // 262144 u16
  float* osel  = (float*)(vt + (size_t)HKV * DH * S_LEN);    // 2097152 f
  size_t need  = (size_t)((char*)(osel + (size_t)S_LEN * HQ * DH) - (char*)d_ws);

  nsa_conv_kernel<<<HKV * SC, 256, 0, stream>>>(k, v, wk, wv, ck, cv);
  nsa_prep_kernel<<<128, 256, 0, stream>>>(q, k, v, wg, kb, vt, gates);
  nsa_cmp_kernel<<<HKV * (S_LEN / 4), 256, 0, stream>>>(q, ck, cv, gates, out, sel);
  if (ws_size >= need) {
    nsa_selswa_kernel<<<2 * HKV * 256, 256, 0, stream>>>(q, kb, vt, gates, sel, out, osel, 2);
    nsa_merge_kernel<<<(S_LEN * HQ * DH / 4) / 256, 256, 0, stream>>>(osel, out);
  } else {
    nsa_selswa_kernel<<<HKV * 256, 256, 0, stream>>>(q, kb, vt, gates, sel, out, osel, 0);
    nsa_selswa_kernel<<<HKV * 256, 256, 0, stream>>>(q, kb, vt, gates, sel, out, osel, 1);
  }
}